// Round 11
// baseline (156.894 us; speedup 1.0000x reference)
//
#include <hip/hip_runtime.h>
#include <stdint.h>

// KANLinear fused kernel v10 for MI355X (gfx950).
// out = x @ bw + scaling * einsum('bik,iok->bo', basis(x), sw)
// One bf16 MFMA GEMM: K = 256 i-slabs x 80 (66 basis + base at k=66 + zero pad).
// v10 = v9 (best: main 76.8us, total 148.3) + WINDOWED basis ported into the
// BM=128 / 4-threads-per-row structure:
//   - q<3 computes window group g0+q (8 exp evals; 24/row vs 96/row in v9).
//     Window groups g0..g0+2 cover [ikc-8, ikc+8]; excluded slots <= e^-41.8
//     -> bv <= 1e-11 (validated absmax 0.03125 in v4b-v8).
//   - zero-fill: thread q writes non-window groups zq=q and q+4 (zg = zq<g0 ?
//     zq : zq+3); group 8 gets {0, cvtpk(x,0), 0, 0} (slot 66 = base term) or
//     the in-window h=1 override when g0>=6.
//   - window sum: same 2 shfl_xor over the 4-lane row group (q=3 adds 0).
// Latency note: STEP issues LOADB(next) BEFORE the 20-MFMA block, so B-loads
// land under MFMA+BASIS even with the shorter BASIS (v4b's trap was LOADB
// after MFMA with nothing to hide under).
// Everything else verbatim v9: BM=128, (512,2), 64x64 wave tiles, grid 256,
// dbuf breg[2][10], cvtpk + exp2 builtins, split-K partials + reduce.

#define IN_F 256
#define OUT_F 256
#define NB 66
#define KP 80        // padded K per i-slab: 66 basis + base at k=66 + zeros, = 5 x K16
#define APAD 88      // A LDS row stride in ushorts
#define KSPLIT 8
#define SLABS 32     // IN_F / KSPLIT
#define BM 128
#define NTHREADS 512

typedef __attribute__((ext_vector_type(8))) short bf16x8;
typedef __attribute__((ext_vector_type(16))) float f32x16;

__device__ __forceinline__ unsigned int cvtpk(float lo, float hi) {
  unsigned int r;
  asm("v_cvt_pk_bf16_f32 %0, %1, %2" : "=v"(r) : "v"(lo), "v"(hi));
  return r;   // [15:0]=bf16(lo), [31:16]=bf16(hi), RNE
}

// ---- scaling partial: block b sums i in [b*32, b*32+32); pack kernel finishes the mean ----
__global__ void kan_scale8(const float* __restrict__ sca, float* __restrict__ wsp) {
  const int o = threadIdx.x, b = blockIdx.x;
  float s = 0.0f;
  #pragma unroll
  for (int j = 0; j < 32; j++) {
    const int i = b * 32 + j;
    s += fmaxf(sca[(size_t)i * OUT_F + o], 1e-7f);
  }
  wsp[b * OUT_F + o] = s;
}

// ---- pack W' -> wp2, layout (i*10 + g)*256 + o of 8-bf16 chunks, g = kk*2+half ----
// k<66 = sw*scaling[o]; k=66 = bw; 67..79 = 0. Coalesced uint4 stores.
__global__ void kan_pack(const float* __restrict__ sw, const float* __restrict__ bw,
                         const float* __restrict__ wsp, unsigned short* __restrict__ wp2) {
  const int i = blockIdx.x, o = threadIdx.x;
  float sc = 0.0f;
  #pragma unroll
  for (int b = 0; b < 8; b++) sc += wsp[b * OUT_F + o];
  sc *= (1.0f / 256.0f);
  const float2* src = (const float2*)(sw + ((size_t)i * OUT_F + o) * NB);
  float v[80];
  #pragma unroll
  for (int j = 0; j < 33; j++) {
    float2 t2 = src[j];
    v[2 * j] = t2.x * sc;
    v[2 * j + 1] = t2.y * sc;
  }
  v[66] = bw[(size_t)i * OUT_F + o];
  #pragma unroll
  for (int k = 67; k < 80; k++) v[k] = 0.0f;
  uint4* dst = (uint4*)wp2;
  #pragma unroll
  for (int g = 0; g < 10; g++) {
    uint4 u;
    unsigned int* up = (unsigned int*)&u;
    #pragma unroll
    for (int h = 0; h < 4; h++)
      up[h] = cvtpk(v[g * 8 + 2 * h], v[g * 8 + 2 * h + 1]);
    dst[((size_t)i * 10 + g) * OUT_F + o] = u;
  }
}

// ---- main fused GEMM ----
__global__ __launch_bounds__(NTHREADS, 2) void kan_main(
    const float* __restrict__ x, const unsigned short* __restrict__ wp2,
    float* __restrict__ dst, int atomic_mode) {
  __shared__ unsigned short A[2][BM * APAD];   // 45056 B

  const int t = threadIdx.x;
  const int lane = t & 63;
  const int w = t >> 6;            // 0..7
  const int ml = lane & 31;
  const int half = lane >> 5;
  const int mr = w >> 2;           // wave M-row: 0..1 (64 rows each)
  const int nc = w & 3;            // wave N-col: 0..3 (64 cols each)
  const int mblk = (int)blockIdx.x >> 3;
  const int kidx = (int)blockIdx.x & 7;   // XCD-affine split-K index
  const int b0 = mblk * BM;
  const int ibase = kidx * SLABS;

  // basis thread mapping: row rb = t>>2, 4 threads/row; q<3 = exp threads
  const int rb = t >> 2;           // 0..127
  const int q = t & 3;

  const float* xrow = x + (size_t)(b0 + rb) * IN_F;
  const int boff = (nc * 64 + ml) * 8;   // ushort offset of this lane's B row chunk

  bf16x8 breg[2][10];
  f32x16 acc[4] = {f32x16{}, f32x16{}, f32x16{}, f32x16{}};

#define LOADB(P, ISLAB)                                                        \
  {                                                                            \
    const unsigned short* bp =                                                 \
        wp2 + (size_t)(ISLAB) * (OUT_F * KP) + half * 2048 + boff;             \
    _Pragma("unroll") for (int kk = 0; kk < 5; kk++) {                         \
      breg[P][kk] = *(const bf16x8*)(bp + kk * 4096);                          \
      breg[P][5 + kk] = *(const bf16x8*)(bp + kk * 4096 + 256);                \
    }                                                                          \
  }

// Windowed basis, 4 threads/row: ikc = clamp(round(65*tl),0,65);
// g0 = max((ikc-8)>>3, 0) <= 7. q<3: exp group g0+q. Zero groups (7 of 10):
// zq = q and q+4 (q<3); zg = zq<g0 ? zq : zq+3. Slot 66 (group 8, word 1 lo)
// carries the base term x.
#define BASIS(BUFSEL, XVAL)                                                    \
  {                                                                            \
    const float xr_ = (XVAL);                                                  \
    const float xc_ = fminf(fmaxf(xr_, -1.0f), 1.0f);                          \
    const float xs_ = (xc_ + 1.0f) * (63.0f / (2.0f + 1e-7f));                 \
    const float tl_ = xs_ - fminf(floorf(xs_), 61.0f);                         \
    const int ikc_ = min((int)(tl_ * 65.0f + 0.5f), 65);                       \
    const int g0_ = max((ikc_ - 8) >> 3, 0);                                   \
    unsigned short* Arow_ = &A[BUFSEL][rb * APAD];                             \
    const int kbase_ = (g0_ + q) * 8;                                          \
    float e_[8];                                                               \
    float s_ = 0.0f;                                                           \
    if (q < 3) {                                                               \
      const float tb_ = tl_ - (float)kbase_ * (1.0f / 65.0f);                  \
      _Pragma("unroll") for (int j = 0; j < 8; j++) {                          \
        const float d_ = tb_ - (float)j * (1.0f / 65.0f);                      \
        float ee = __builtin_amdgcn_exp2f(-3142.1892f * d_ * d_);              \
        ee = (kbase_ + j < 66) ? ee : 0.0f;                                    \
        e_[j] = ee;                                                            \
        s_ += ee;                                                              \
      }                                                                        \
    }                                                                          \
    s_ += __shfl_xor(s_, 1);                                                   \
    s_ += __shfl_xor(s_, 2);                                                   \
    const float r_ = __fdividef(1.0f, s_ + 1e-7f);                             \
    const unsigned int bu_ = cvtpk(xr_, 0.0f);                                 \
    const uint4 z_ = {0u, 0u, 0u, 0u};                                         \
    const uint4 b_ = {0u, bu_, 0u, 0u};   /* slot 66 = word1.lo of group 8 */  \
    if (q < 3) {                                                               \
      uint4 u_;                                                                \
      unsigned int* up_ = (unsigned int*)&u_;                                  \
      _Pragma("unroll") for (int h = 0; h < 4; h++) {                          \
        float f0 = e_[2 * h] * r_;                                             \
        const float f1 = e_[2 * h + 1] * r_;                                   \
        f0 = (kbase_ + 2 * h == 66) ? xr_ : f0;   /* 66 even: f1 unaffected */ \
        up_[h] = cvtpk(f0, f1);                                                \
      }                                                                        \
      *(uint4*)(Arow_ + kbase_) = u_;                                          \
      const int zq2_ = q + 4;                                                  \
      const int zg2_ = (zq2_ < g0_) ? zq2_ : zq2_ + 3;                         \
      *(uint4*)(Arow_ + zg2_ * 8) = (zg2_ == 8) ? b_ : z_;                     \
    }                                                                          \
    const int zg1_ = (q < g0_) ? q : q + 3;                                    \
    *(uint4*)(Arow_ + zg1_ * 8) = (zg1_ == 8) ? b_ : z_;                       \
  }

#define MFMA_SLAB(CUR, P)                                                      \
  {                                                                            \
    const unsigned short* Ac = &A[CUR][0];                                     \
    _Pragma("unroll") for (int kk = 0; kk < 5; kk++) {                         \
      const int ko = kk * 16 + half * 8;                                       \
      bf16x8 a0 = *(const bf16x8*)(Ac + (mr * 64 + ml) * APAD + ko);           \
      bf16x8 a1 = *(const bf16x8*)(Ac + (mr * 64 + 32 + ml) * APAD + ko);      \
      acc[0] = __builtin_amdgcn_mfma_f32_32x32x16_bf16(a0, breg[P][kk], acc[0], 0, 0, 0);       \
      acc[1] = __builtin_amdgcn_mfma_f32_32x32x16_bf16(a0, breg[P][5 + kk], acc[1], 0, 0, 0);   \
      acc[2] = __builtin_amdgcn_mfma_f32_32x32x16_bf16(a1, breg[P][kk], acc[2], 0, 0, 0);       \
      acc[3] = __builtin_amdgcn_mfma_f32_32x32x16_bf16(a1, breg[P][5 + kk], acc[3], 0, 0, 0);   \
    }                                                                          \
  }

  // ---- prologue: slab 0 basis + B regs ----
  BASIS(0, xrow[ibase]);
  LOADB(0, ibase);
  float xn = xrow[ibase + 1];
  __syncthreads();

#define STEP(II, P)                                                            \
  {                                                                            \
    if ((II) + 1 < SLABS) LOADB(1 - (P), ibase + (II) + 1);                    \
    MFMA_SLAB((II) & 1, P);                                                    \
    const float xc2 = xn;                                                      \
    if ((II) + 2 < SLABS) xn = xrow[ibase + (II) + 2];                         \
    if ((II) + 1 < SLABS) BASIS(((II) + 1) & 1, xc2);                          \
    __syncthreads();                                                           \
  }

  for (int ii = 0; ii < SLABS; ii += 2) {
    STEP(ii, 0);
    STEP(ii + 1, 1);
  }

  // ---- epilogue: C/D layout col=lane&31, row=(r&3)+8*(r>>2)+4*(lane>>5) ----
  const int colb = nc * 64 + ml;
  if (atomic_mode) {
    #pragma unroll
    for (int mb = 0; mb < 2; mb++) {
      #pragma unroll
      for (int r = 0; r < 16; r++) {
        const int row = b0 + mr * 64 + mb * 32 + (r & 3) + 8 * (r >> 2) + 4 * half;
        atomicAdd(&dst[(size_t)row * OUT_F + colb], acc[mb * 2][r]);
        atomicAdd(&dst[(size_t)row * OUT_F + colb + 32], acc[mb * 2 + 1][r]);
      }
    }
  } else {
    float* pd = dst + (size_t)kidx * ((size_t)4096 * OUT_F);
    #pragma unroll
    for (int mb = 0; mb < 2; mb++) {
      #pragma unroll
      for (int r = 0; r < 16; r++) {
        const int row = b0 + mr * 64 + mb * 32 + (r & 3) + 8 * (r >> 2) + 4 * half;
        pd[(size_t)row * OUT_F + colb] = acc[mb * 2][r];
        pd[(size_t)row * OUT_F + colb + 32] = acc[mb * 2 + 1][r];
      }
    }
  }
}

// ---- split-K reduce: out = sum of 8 partial tiles ----
__global__ void kan_reduce(const float* __restrict__ part, float* __restrict__ out) {
  const size_t j = ((size_t)blockIdx.x * 256 + threadIdx.x) * 4;
  float4 a = *(const float4*)(part + j);
  #pragma unroll
  for (int s = 1; s < 8; s++) {
    float4 b = *(const float4*)(part + (size_t)s * 1048576 + j);
    a.x += b.x; a.y += b.y; a.z += b.z; a.w += b.w;
  }
  *(float4*)(out + j) = a;
}

// ---- naive fallback (only if d_ws is too small): correct, slow ----
__global__ void kan_naive(const float* __restrict__ x, const float* __restrict__ bw,
                          const float* __restrict__ sw, const float* __restrict__ sca,
                          float* __restrict__ out) {
  const int o = threadIdx.x;
  const int b = blockIdx.x;
  float accb = 0.0f, accs = 0.0f, scl = 0.0f;
  for (int i = 0; i < IN_F; i++) {
    const float xraw = x[(size_t)b * IN_F + i];
    accb += xraw * bw[(size_t)i * OUT_F + o];
    scl += fmaxf(sca[(size_t)i * OUT_F + o], 1e-7f);
    const float xc = fminf(fmaxf(xraw, -1.0f), 1.0f);
    const float xs = (xc + 1.0f) * (63.0f / (2.0f + 1e-7f));
    const float tl = xs - fminf(floorf(xs), 61.0f);
    const int kc = (int)(tl * 65.0f + 0.5f);
    const int k0 = max(0, min(kc - 8, 50));
    float e[16]; float s = 0.0f;
    #pragma unroll
    for (int j = 0; j < 16; j++) {
      float d = tl - (float)(k0 + j) * (1.0f / 65.0f);
      e[j] = __expf(-2178.0f * d * d);
      s += e[j];
    }
    const float r = __fdividef(1.0f, s + 1e-7f);
    const float* wrow = sw + ((size_t)i * OUT_F + o) * NB + k0;
    float dot = 0.0f;
    #pragma unroll
    for (int j = 0; j < 16; j++) dot += e[j] * wrow[j];
    accs += dot * r;
  }
  out[(size_t)b * OUT_F + o] = accb + accs * (scl * (1.0f / 256.0f));
}

extern "C" void kernel_launch(void* const* d_in, const int* in_sizes, int n_in,
                              void* d_out, int out_size, void* d_ws, size_t ws_size,
                              hipStream_t stream) {
  const float* x   = (const float*)d_in[0];
  const float* bw  = (const float*)d_in[1];
  const float* sw  = (const float*)d_in[2];
  const float* sca = (const float*)d_in[3];
  float* out = (float*)d_out;

  const size_t WP2_BYTES  = (size_t)IN_F * OUT_F * KP * 2;          // 10485760
  const size_t WP_OFF     = 8192;                                   // after wsp[8][256]
  const size_t PART_OFF   = WP_OFF + WP2_BYTES;                     // 10493952
  const size_t PART_BYTES = (size_t)KSPLIT * 4096 * OUT_F * 4;      // 33554432

  if (ws_size >= PART_OFF + PART_BYTES) {
    float* wsp = (float*)d_ws;
    unsigned short* wp2 = (unsigned short*)((char*)d_ws + WP_OFF);
    float* part = (float*)((char*)d_ws + PART_OFF);
    kan_scale8<<<8, 256, 0, stream>>>(sca, wsp);
    kan_pack<<<256, 256, 0, stream>>>(sw, bw, wsp, wp2);
    kan_main<<<256, NTHREADS, 0, stream>>>(x, wp2, part, 0);
    kan_reduce<<<1024, 256, 0, stream>>>(part, out);
  } else if (ws_size >= PART_OFF) {
    float* wsp = (float*)d_ws;
    unsigned short* wp2 = (unsigned short*)((char*)d_ws + WP_OFF);
    (void)hipMemsetAsync(d_out, 0, (size_t)out_size * sizeof(float), stream);
    kan_scale8<<<8, 256, 0, stream>>>(sca, wsp);
    kan_pack<<<256, 256, 0, stream>>>(sw, bw, wsp, wp2);
    kan_main<<<256, NTHREADS, 0, stream>>>(x, wp2, out, 1);
  } else {
    kan_naive<<<4096, 256, 0, stream>>>(x, bw, sw, sca, out);
  }
}

// Round 12
// 150.221 us; speedup vs baseline: 1.0444x; 1.0444x over previous
//
#include <hip/hip_runtime.h>
#include <stdint.h>

// KANLinear fused kernel v11 for MI355X (gfx950).
// out = x @ bw + scaling * einsum('bik,iok->bo', basis(x), sw)
// One bf16 MFMA GEMM: K = 256 i-slabs x 80 (66 basis + base at k=66 + zero pad).
// v11 vs v10 (main 78us flat despite VALU 36.8->20.5): kernel is latency-idle,
// not pipe-bound; 1 barrier-locked wave group/CU (164 unified regs -> 8-wave
// blocks quantize occupancy to 2 waves/SIMD). Fix WITHOUT thinning waves
// (v5/v8 lesson: fat 64x64 waves minimize fragment traffic):
//   - BM 128->64, NTHREADS 512->256: 4 fat 64x64 waves/block (nc=w, no mr),
//     grid 512 -> 2 blocks/CU. Per-CU totals identical to v10 (LDS reads, L2-B
//     with zero mr-redundancy, basis rows 2x64 vs 1x128, regs/wave). Only
//     change: TWO independent barrier groups fill each other's latency gaps.
//   - windowed BASIS (v10, 4 threads/row) verbatim; cvtpk + exp2 builtins.
// Launcher/workspace identical to v10 (KSPLIT=8 partials + reduce).

#define IN_F 256
#define OUT_F 256
#define NB 66
#define KP 80        // padded K per i-slab: 66 basis + base at k=66 + zeros, = 5 x K16
#define APAD 88      // A LDS row stride in ushorts
#define KSPLIT 8
#define SLABS 32     // IN_F / KSPLIT
#define BM 64
#define NTHREADS 256
#define GRID_MAIN 512   // (4096/BM) * KSPLIT

typedef __attribute__((ext_vector_type(8))) short bf16x8;
typedef __attribute__((ext_vector_type(16))) float f32x16;

__device__ __forceinline__ unsigned int cvtpk(float lo, float hi) {
  unsigned int r;
  asm("v_cvt_pk_bf16_f32 %0, %1, %2" : "=v"(r) : "v"(lo), "v"(hi));
  return r;   // [15:0]=bf16(lo), [31:16]=bf16(hi), RNE
}

// ---- scaling partial: block b sums i in [b*32, b*32+32); pack kernel finishes the mean ----
__global__ void kan_scale8(const float* __restrict__ sca, float* __restrict__ wsp) {
  const int o = threadIdx.x, b = blockIdx.x;
  float s = 0.0f;
  #pragma unroll
  for (int j = 0; j < 32; j++) {
    const int i = b * 32 + j;
    s += fmaxf(sca[(size_t)i * OUT_F + o], 1e-7f);
  }
  wsp[b * OUT_F + o] = s;
}

// ---- pack W' -> wp2, layout (i*10 + g)*256 + o of 8-bf16 chunks, g = kk*2+half ----
// k<66 = sw*scaling[o]; k=66 = bw; 67..79 = 0. Coalesced uint4 stores.
__global__ void kan_pack(const float* __restrict__ sw, const float* __restrict__ bw,
                         const float* __restrict__ wsp, unsigned short* __restrict__ wp2) {
  const int i = blockIdx.x, o = threadIdx.x;
  float sc = 0.0f;
  #pragma unroll
  for (int b = 0; b < 8; b++) sc += wsp[b * OUT_F + o];
  sc *= (1.0f / 256.0f);
  const float2* src = (const float2*)(sw + ((size_t)i * OUT_F + o) * NB);
  float v[80];
  #pragma unroll
  for (int j = 0; j < 33; j++) {
    float2 t2 = src[j];
    v[2 * j] = t2.x * sc;
    v[2 * j + 1] = t2.y * sc;
  }
  v[66] = bw[(size_t)i * OUT_F + o];
  #pragma unroll
  for (int k = 67; k < 80; k++) v[k] = 0.0f;
  uint4* dst = (uint4*)wp2;
  #pragma unroll
  for (int g = 0; g < 10; g++) {
    uint4 u;
    unsigned int* up = (unsigned int*)&u;
    #pragma unroll
    for (int h = 0; h < 4; h++)
      up[h] = cvtpk(v[g * 8 + 2 * h], v[g * 8 + 2 * h + 1]);
    dst[((size_t)i * 10 + g) * OUT_F + o] = u;
  }
}

// ---- main fused GEMM: 4 waves x (64x64), 2 blocks/CU ----
__global__ __launch_bounds__(NTHREADS, 2) void kan_main(
    const float* __restrict__ x, const unsigned short* __restrict__ wp2,
    float* __restrict__ dst, int atomic_mode) {
  __shared__ unsigned short A[2][BM * APAD];   // 22528 B

  const int t = threadIdx.x;
  const int lane = t & 63;
  const int nc = t >> 6;           // 0..3: wave N-col (64 cols each); all rows
  const int ml = lane & 31;
  const int half = lane >> 5;
  const int mblk = (int)blockIdx.x >> 3;
  const int kidx = (int)blockIdx.x & 7;   // XCD-affine split-K index
  const int b0 = mblk * BM;
  const int ibase = kidx * SLABS;

  // basis thread mapping: row rb = t>>2, 4 threads/row; q<3 = exp threads
  const int rb = t >> 2;           // 0..63
  const int q = t & 3;

  const float* xrow = x + (size_t)(b0 + rb) * IN_F;
  const int boff = (nc * 64 + ml) * 8;   // ushort offset of this lane's B row chunk

  bf16x8 breg[2][10];
  f32x16 acc[4] = {f32x16{}, f32x16{}, f32x16{}, f32x16{}};

#define LOADB(P, ISLAB)                                                        \
  {                                                                            \
    const unsigned short* bp =                                                 \
        wp2 + (size_t)(ISLAB) * (OUT_F * KP) + half * 2048 + boff;             \
    _Pragma("unroll") for (int kk = 0; kk < 5; kk++) {                         \
      breg[P][kk] = *(const bf16x8*)(bp + kk * 4096);                          \
      breg[P][5 + kk] = *(const bf16x8*)(bp + kk * 4096 + 256);                \
    }                                                                          \
  }

// Windowed basis, 4 threads/row (v10, validated): ikc = clamp(round(65*tl),0,65);
// g0 = max((ikc-8)>>3, 0) <= 7. q<3: exp group g0+q (8 evals; excluded slots
// <= e^-41.8 -> bv <= 1e-11). Zero groups: zq = q and q+4 (q<3); zg = zq<g0 ?
// zq : zq+3. Slot 66 (group 8, word1 lo) carries the base term x.
#define BASIS(BUFSEL, XVAL)                                                    \
  {                                                                            \
    const float xr_ = (XVAL);                                                  \
    const float xc_ = fminf(fmaxf(xr_, -1.0f), 1.0f);                          \
    const float xs_ = (xc_ + 1.0f) * (63.0f / (2.0f + 1e-7f));                 \
    const float tl_ = xs_ - fminf(floorf(xs_), 61.0f);                         \
    const int ikc_ = min((int)(tl_ * 65.0f + 0.5f), 65);                       \
    const int g0_ = max((ikc_ - 8) >> 3, 0);                                   \
    unsigned short* Arow_ = &A[BUFSEL][rb * APAD];                             \
    const int kbase_ = (g0_ + q) * 8;                                          \
    float e_[8];                                                               \
    float s_ = 0.0f;                                                           \
    if (q < 3) {                                                               \
      const float tb_ = tl_ - (float)kbase_ * (1.0f / 65.0f);                  \
      _Pragma("unroll") for (int j = 0; j < 8; j++) {                          \
        const float d_ = tb_ - (float)j * (1.0f / 65.0f);                      \
        float ee = __builtin_amdgcn_exp2f(-3142.1892f * d_ * d_);              \
        ee = (kbase_ + j < 66) ? ee : 0.0f;                                    \
        e_[j] = ee;                                                            \
        s_ += ee;                                                              \
      }                                                                        \
    }                                                                          \
    s_ += __shfl_xor(s_, 1);                                                   \
    s_ += __shfl_xor(s_, 2);                                                   \
    const float r_ = __fdividef(1.0f, s_ + 1e-7f);                             \
    const unsigned int bu_ = cvtpk(xr_, 0.0f);                                 \
    const uint4 z_ = {0u, 0u, 0u, 0u};                                         \
    const uint4 b_ = {0u, bu_, 0u, 0u};   /* slot 66 = word1.lo of group 8 */  \
    if (q < 3) {                                                               \
      uint4 u_;                                                                \
      unsigned int* up_ = (unsigned int*)&u_;                                  \
      _Pragma("unroll") for (int h = 0; h < 4; h++) {                          \
        float f0 = e_[2 * h] * r_;                                             \
        const float f1 = e_[2 * h + 1] * r_;                                   \
        f0 = (kbase_ + 2 * h == 66) ? xr_ : f0;   /* 66 even: f1 unaffected */ \
        up_[h] = cvtpk(f0, f1);                                                \
      }                                                                        \
      *(uint4*)(Arow_ + kbase_) = u_;                                          \
      const int zq2_ = q + 4;                                                  \
      const int zg2_ = (zq2_ < g0_) ? zq2_ : zq2_ + 3;                         \
      *(uint4*)(Arow_ + zg2_ * 8) = (zg2_ == 8) ? b_ : z_;                     \
    }                                                                          \
    const int zg1_ = (q < g0_) ? q : q + 3;                                    \
    *(uint4*)(Arow_ + zg1_ * 8) = (zg1_ == 8) ? b_ : z_;                       \
  }

#define MFMA_SLAB(CUR, P)                                                      \
  {                                                                            \
    const unsigned short* Ac = &A[CUR][0];                                     \
    _Pragma("unroll") for (int kk = 0; kk < 5; kk++) {                         \
      const int ko = kk * 16 + half * 8;                                       \
      bf16x8 a0 = *(const bf16x8*)(Ac + ml * APAD + ko);                       \
      bf16x8 a1 = *(const bf16x8*)(Ac + (32 + ml) * APAD + ko);                \
      acc[0] = __builtin_amdgcn_mfma_f32_32x32x16_bf16(a0, breg[P][kk], acc[0], 0, 0, 0);       \
      acc[1] = __builtin_amdgcn_mfma_f32_32x32x16_bf16(a0, breg[P][5 + kk], acc[1], 0, 0, 0);   \
      acc[2] = __builtin_amdgcn_mfma_f32_32x32x16_bf16(a1, breg[P][kk], acc[2], 0, 0, 0);       \
      acc[3] = __builtin_amdgcn_mfma_f32_32x32x16_bf16(a1, breg[P][5 + kk], acc[3], 0, 0, 0);   \
    }                                                                          \
  }

  // ---- prologue: slab 0 basis + B regs ----
  BASIS(0, xrow[ibase]);
  LOADB(0, ibase);
  float xn = xrow[ibase + 1];
  __syncthreads();

#define STEP(II, P)                                                            \
  {                                                                            \
    if ((II) + 1 < SLABS) LOADB(1 - (P), ibase + (II) + 1);                    \
    MFMA_SLAB((II) & 1, P);                                                    \
    const float xc2 = xn;                                                      \
    if ((II) + 2 < SLABS) xn = xrow[ibase + (II) + 2];                         \
    if ((II) + 1 < SLABS) BASIS(((II) + 1) & 1, xc2);                          \
    __syncthreads();                                                           \
  }

  for (int ii = 0; ii < SLABS; ii += 2) {
    STEP(ii, 0);
    STEP(ii + 1, 1);
  }

  // ---- epilogue: C/D layout col=lane&31, row=(r&3)+8*(r>>2)+4*(lane>>5) ----
  const int colb = nc * 64 + ml;
  if (atomic_mode) {
    #pragma unroll
    for (int mb = 0; mb < 2; mb++) {
      #pragma unroll
      for (int r = 0; r < 16; r++) {
        const int row = b0 + mb * 32 + (r & 3) + 8 * (r >> 2) + 4 * half;
        atomicAdd(&dst[(size_t)row * OUT_F + colb], acc[mb * 2][r]);
        atomicAdd(&dst[(size_t)row * OUT_F + colb + 32], acc[mb * 2 + 1][r]);
      }
    }
  } else {
    float* pd = dst + (size_t)kidx * ((size_t)4096 * OUT_F);
    #pragma unroll
    for (int mb = 0; mb < 2; mb++) {
      #pragma unroll
      for (int r = 0; r < 16; r++) {
        const int row = b0 + mb * 32 + (r & 3) + 8 * (r >> 2) + 4 * half;
        pd[(size_t)row * OUT_F + colb] = acc[mb * 2][r];
        pd[(size_t)row * OUT_F + colb + 32] = acc[mb * 2 + 1][r];
      }
    }
  }
}

// ---- split-K reduce: out = sum of 8 partial tiles ----
__global__ void kan_reduce(const float* __restrict__ part, float* __restrict__ out) {
  const size_t j = ((size_t)blockIdx.x * 256 + threadIdx.x) * 4;
  float4 a = *(const float4*)(part + j);
  #pragma unroll
  for (int s = 1; s < 8; s++) {
    float4 b = *(const float4*)(part + (size_t)s * 1048576 + j);
    a.x += b.x; a.y += b.y; a.z += b.z; a.w += b.w;
  }
  *(float4*)(out + j) = a;
}

// ---- naive fallback (only if d_ws is too small): correct, slow ----
__global__ void kan_naive(const float* __restrict__ x, const float* __restrict__ bw,
                          const float* __restrict__ sw, const float* __restrict__ sca,
                          float* __restrict__ out) {
  const int o = threadIdx.x;
  const int b = blockIdx.x;
  float accb = 0.0f, accs = 0.0f, scl = 0.0f;
  for (int i = 0; i < IN_F; i++) {
    const float xraw = x[(size_t)b * IN_F + i];
    accb += xraw * bw[(size_t)i * OUT_F + o];
    scl += fmaxf(sca[(size_t)i * OUT_F + o], 1e-7f);
    const float xc = fminf(fmaxf(xraw, -1.0f), 1.0f);
    const float xs = (xc + 1.0f) * (63.0f / (2.0f + 1e-7f));
    const float tl = xs - fminf(floorf(xs), 61.0f);
    const int kc = (int)(tl * 65.0f + 0.5f);
    const int k0 = max(0, min(kc - 8, 50));
    float e[16]; float s = 0.0f;
    #pragma unroll
    for (int j = 0; j < 16; j++) {
      float d = tl - (float)(k0 + j) * (1.0f / 65.0f);
      e[j] = __expf(-2178.0f * d * d);
      s += e[j];
    }
    const float r = __fdividef(1.0f, s + 1e-7f);
    const float* wrow = sw + ((size_t)i * OUT_F + o) * NB + k0;
    float dot = 0.0f;
    #pragma unroll
    for (int j = 0; j < 16; j++) dot += e[j] * wrow[j];
    accs += dot * r;
  }
  out[(size_t)b * OUT_F + o] = accb + accs * (scl * (1.0f / 256.0f));
}

extern "C" void kernel_launch(void* const* d_in, const int* in_sizes, int n_in,
                              void* d_out, int out_size, void* d_ws, size_t ws_size,
                              hipStream_t stream) {
  const float* x   = (const float*)d_in[0];
  const float* bw  = (const float*)d_in[1];
  const float* sw  = (const float*)d_in[2];
  const float* sca = (const float*)d_in[3];
  float* out = (float*)d_out;

  const size_t WP2_BYTES  = (size_t)IN_F * OUT_F * KP * 2;          // 10485760
  const size_t WP_OFF     = 8192;                                   // after wsp[8][256]
  const size_t PART_OFF   = WP_OFF + WP2_BYTES;                     // 10493952
  const size_t PART_BYTES = (size_t)KSPLIT * 4096 * OUT_F * 4;      // 33554432

  if (ws_size >= PART_OFF + PART_BYTES) {
    float* wsp = (float*)d_ws;
    unsigned short* wp2 = (unsigned short*)((char*)d_ws + WP_OFF);
    float* part = (float*)((char*)d_ws + PART_OFF);
    kan_scale8<<<8, 256, 0, stream>>>(sca, wsp);
    kan_pack<<<256, 256, 0, stream>>>(sw, bw, wsp, wp2);
    kan_main<<<GRID_MAIN, NTHREADS, 0, stream>>>(x, wp2, part, 0);
    kan_reduce<<<1024, 256, 0, stream>>>(part, out);
  } else if (ws_size >= PART_OFF) {
    float* wsp = (float*)d_ws;
    unsigned short* wp2 = (unsigned short*)((char*)d_ws + WP_OFF);
    (void)hipMemsetAsync(d_out, 0, (size_t)out_size * sizeof(float), stream);
    kan_scale8<<<8, 256, 0, stream>>>(sca, wsp);
    kan_pack<<<256, 256, 0, stream>>>(sw, bw, wsp, wp2);
    kan_main<<<GRID_MAIN, NTHREADS, 0, stream>>>(x, wp2, out, 1);
  } else {
    kan_naive<<<4096, 256, 0, stream>>>(x, bw, sw, sca, out);
  }
}

// Round 13
// 143.093 us; speedup vs baseline: 1.0964x; 1.0498x over previous
//
#include <hip/hip_runtime.h>
#include <stdint.h>

// KANLinear fused kernel v12 for MI355X (gfx950).
// out = x @ bw + scaling * einsum('bik,iok->bo', basis(x), sw)
// One bf16 MFMA GEMM: K = 256 i-slabs x 80 (66 basis + base at k=66 + zero pad).
// v12 = v11 (best main 73.7us: BM=64, 4x(64x64) waves, 2 blocks/CU, windowed
// BASIS) + two scheduling changes:
//   - RAW BARRIER: __syncthreads() -> { s_waitcnt lgkmcnt(0); s_barrier }.
//     HIP's __syncthreads drains vmcnt(0) too, stalling each STEP on the
//     just-issued next-slab B-loads (register-destined, private -- no sync
//     needed). Barrier only orders LDS (BASIS writes / MFMA reads; dbuf WAR
//     is parity-safe). Compiler still emits precise vmcnt(N) before breg use.
//     This is the AITER counted-vmcnt benefit at source level.
//   - s_setprio(1) around the MFMA cluster (T5): 2 independent blocks/CU =
//     phase-diverse waves, the regime where setprio measured +4-7%.
// Everything else verbatim v11.

#define IN_F 256
#define OUT_F 256
#define NB 66
#define KP 80        // padded K per i-slab: 66 basis + base at k=66 + zeros, = 5 x K16
#define APAD 88      // A LDS row stride in ushorts
#define KSPLIT 8
#define SLABS 32     // IN_F / KSPLIT
#define BM 64
#define NTHREADS 256
#define GRID_MAIN 512   // (4096/BM) * KSPLIT

typedef __attribute__((ext_vector_type(8))) short bf16x8;
typedef __attribute__((ext_vector_type(16))) float f32x16;

__device__ __forceinline__ unsigned int cvtpk(float lo, float hi) {
  unsigned int r;
  asm("v_cvt_pk_bf16_f32 %0, %1, %2" : "=v"(r) : "v"(lo), "v"(hi));
  return r;   // [15:0]=bf16(lo), [31:16]=bf16(hi), RNE
}

// LDS-only barrier: drain ds ops, keep global loads in flight.
#define BAR()                                                                  \
  {                                                                            \
    asm volatile("s_waitcnt lgkmcnt(0)" ::: "memory");                         \
    __builtin_amdgcn_s_barrier();                                              \
  }

// ---- scaling partial: block b sums i in [b*32, b*32+32); pack kernel finishes the mean ----
__global__ void kan_scale8(const float* __restrict__ sca, float* __restrict__ wsp) {
  const int o = threadIdx.x, b = blockIdx.x;
  float s = 0.0f;
  #pragma unroll
  for (int j = 0; j < 32; j++) {
    const int i = b * 32 + j;
    s += fmaxf(sca[(size_t)i * OUT_F + o], 1e-7f);
  }
  wsp[b * OUT_F + o] = s;
}

// ---- pack W' -> wp2, layout (i*10 + g)*256 + o of 8-bf16 chunks, g = kk*2+half ----
// k<66 = sw*scaling[o]; k=66 = bw; 67..79 = 0. Coalesced uint4 stores.
__global__ void kan_pack(const float* __restrict__ sw, const float* __restrict__ bw,
                         const float* __restrict__ wsp, unsigned short* __restrict__ wp2) {
  const int i = blockIdx.x, o = threadIdx.x;
  float sc = 0.0f;
  #pragma unroll
  for (int b = 0; b < 8; b++) sc += wsp[b * OUT_F + o];
  sc *= (1.0f / 256.0f);
  const float2* src = (const float2*)(sw + ((size_t)i * OUT_F + o) * NB);
  float v[80];
  #pragma unroll
  for (int j = 0; j < 33; j++) {
    float2 t2 = src[j];
    v[2 * j] = t2.x * sc;
    v[2 * j + 1] = t2.y * sc;
  }
  v[66] = bw[(size_t)i * OUT_F + o];
  #pragma unroll
  for (int k = 67; k < 80; k++) v[k] = 0.0f;
  uint4* dst = (uint4*)wp2;
  #pragma unroll
  for (int g = 0; g < 10; g++) {
    uint4 u;
    unsigned int* up = (unsigned int*)&u;
    #pragma unroll
    for (int h = 0; h < 4; h++)
      up[h] = cvtpk(v[g * 8 + 2 * h], v[g * 8 + 2 * h + 1]);
    dst[((size_t)i * 10 + g) * OUT_F + o] = u;
  }
}

// ---- main fused GEMM: 4 waves x (64x64), 2 blocks/CU ----
__global__ __launch_bounds__(NTHREADS, 2) void kan_main(
    const float* __restrict__ x, const unsigned short* __restrict__ wp2,
    float* __restrict__ dst, int atomic_mode) {
  __shared__ unsigned short A[2][BM * APAD];   // 22528 B

  const int t = threadIdx.x;
  const int lane = t & 63;
  const int nc = t >> 6;           // 0..3: wave N-col (64 cols each); all rows
  const int ml = lane & 31;
  const int half = lane >> 5;
  const int mblk = (int)blockIdx.x >> 3;
  const int kidx = (int)blockIdx.x & 7;   // XCD-affine split-K index
  const int b0 = mblk * BM;
  const int ibase = kidx * SLABS;

  // basis thread mapping: row rb = t>>2, 4 threads/row; q<3 = exp threads
  const int rb = t >> 2;           // 0..63
  const int q = t & 3;

  const float* xrow = x + (size_t)(b0 + rb) * IN_F;
  const int boff = (nc * 64 + ml) * 8;   // ushort offset of this lane's B row chunk

  bf16x8 breg[2][10];
  f32x16 acc[4] = {f32x16{}, f32x16{}, f32x16{}, f32x16{}};

#define LOADB(P, ISLAB)                                                        \
  {                                                                            \
    const unsigned short* bp =                                                 \
        wp2 + (size_t)(ISLAB) * (OUT_F * KP) + half * 2048 + boff;             \
    _Pragma("unroll") for (int kk = 0; kk < 5; kk++) {                         \
      breg[P][kk] = *(const bf16x8*)(bp + kk * 4096);                          \
      breg[P][5 + kk] = *(const bf16x8*)(bp + kk * 4096 + 256);                \
    }                                                                          \
  }

// Windowed basis, 4 threads/row (validated): ikc = clamp(round(65*tl),0,65);
// g0 = max((ikc-8)>>3, 0) <= 7. q<3: exp group g0+q (8 evals; excluded slots
// <= e^-41.8 -> bv <= 1e-11). Zero groups: zq = q and q+4 (q<3); zg = zq<g0 ?
// zq : zq+3. Slot 66 (group 8, word1 lo) carries the base term x.
#define BASIS(BUFSEL, XVAL)                                                    \
  {                                                                            \
    const float xr_ = (XVAL);                                                  \
    const float xc_ = fminf(fmaxf(xr_, -1.0f), 1.0f);                          \
    const float xs_ = (xc_ + 1.0f) * (63.0f / (2.0f + 1e-7f));                 \
    const float tl_ = xs_ - fminf(floorf(xs_), 61.0f);                         \
    const int ikc_ = min((int)(tl_ * 65.0f + 0.5f), 65);                       \
    const int g0_ = max((ikc_ - 8) >> 3, 0);                                   \
    unsigned short* Arow_ = &A[BUFSEL][rb * APAD];                             \
    const int kbase_ = (g0_ + q) * 8;                                          \
    float e_[8];                                                               \
    float s_ = 0.0f;                                                           \
    if (q < 3) {                                                               \
      const float tb_ = tl_ - (float)kbase_ * (1.0f / 65.0f);                  \
      _Pragma("unroll") for (int j = 0; j < 8; j++) {                          \
        const float d_ = tb_ - (float)j * (1.0f / 65.0f);                      \
        float ee = __builtin_amdgcn_exp2f(-3142.1892f * d_ * d_);              \
        ee = (kbase_ + j < 66) ? ee : 0.0f;                                    \
        e_[j] = ee;                                                            \
        s_ += ee;                                                              \
      }                                                                        \
    }                                                                          \
    s_ += __shfl_xor(s_, 1);                                                   \
    s_ += __shfl_xor(s_, 2);                                                   \
    const float r_ = __fdividef(1.0f, s_ + 1e-7f);                             \
    const unsigned int bu_ = cvtpk(xr_, 0.0f);                                 \
    const uint4 z_ = {0u, 0u, 0u, 0u};                                         \
    const uint4 b_ = {0u, bu_, 0u, 0u};   /* slot 66 = word1.lo of group 8 */  \
    if (q < 3) {                                                               \
      uint4 u_;                                                                \
      unsigned int* up_ = (unsigned int*)&u_;                                  \
      _Pragma("unroll") for (int h = 0; h < 4; h++) {                          \
        float f0 = e_[2 * h] * r_;                                             \
        const float f1 = e_[2 * h + 1] * r_;                                   \
        f0 = (kbase_ + 2 * h == 66) ? xr_ : f0;   /* 66 even: f1 unaffected */ \
        up_[h] = cvtpk(f0, f1);                                                \
      }                                                                        \
      *(uint4*)(Arow_ + kbase_) = u_;                                          \
      const int zq2_ = q + 4;                                                  \
      const int zg2_ = (zq2_ < g0_) ? zq2_ : zq2_ + 3;                         \
      *(uint4*)(Arow_ + zg2_ * 8) = (zg2_ == 8) ? b_ : z_;                     \
    }                                                                          \
    const int zg1_ = (q < g0_) ? q : q + 3;                                    \
    *(uint4*)(Arow_ + zg1_ * 8) = (zg1_ == 8) ? b_ : z_;                       \
  }

#define MFMA_SLAB(CUR, P)                                                      \
  {                                                                            \
    const unsigned short* Ac = &A[CUR][0];                                     \
    __builtin_amdgcn_s_setprio(1);                                             \
    _Pragma("unroll") for (int kk = 0; kk < 5; kk++) {                         \
      const int ko = kk * 16 + half * 8;                                       \
      bf16x8 a0 = *(const bf16x8*)(Ac + ml * APAD + ko);                       \
      bf16x8 a1 = *(const bf16x8*)(Ac + (32 + ml) * APAD + ko);                \
      acc[0] = __builtin_amdgcn_mfma_f32_32x32x16_bf16(a0, breg[P][kk], acc[0], 0, 0, 0);       \
      acc[1] = __builtin_amdgcn_mfma_f32_32x32x16_bf16(a0, breg[P][5 + kk], acc[1], 0, 0, 0);   \
      acc[2] = __builtin_amdgcn_mfma_f32_32x32x16_bf16(a1, breg[P][kk], acc[2], 0, 0, 0);       \
      acc[3] = __builtin_amdgcn_mfma_f32_32x32x16_bf16(a1, breg[P][5 + kk], acc[3], 0, 0, 0);   \
    }                                                                          \
    __builtin_amdgcn_s_setprio(0);                                             \
  }

  // ---- prologue: slab 0 basis + B regs ----
  BASIS(0, xrow[ibase]);
  LOADB(0, ibase);
  float xn = xrow[ibase + 1];
  BAR();

#define STEP(II, P)                                                            \
  {                                                                            \
    if ((II) + 1 < SLABS) LOADB(1 - (P), ibase + (II) + 1);                    \
    MFMA_SLAB((II) & 1, P);                                                    \
    const float xc2 = xn;                                                      \
    if ((II) + 2 < SLABS) xn = xrow[ibase + (II) + 2];                         \
    if ((II) + 1 < SLABS) BASIS(((II) + 1) & 1, xc2);                          \
    BAR();                                                                     \
  }

  for (int ii = 0; ii < SLABS; ii += 2) {
    STEP(ii, 0);
    STEP(ii + 1, 1);
  }

  // ---- epilogue: C/D layout col=lane&31, row=(r&3)+8*(r>>2)+4*(lane>>5) ----
  const int colb = nc * 64 + ml;
  if (atomic_mode) {
    #pragma unroll
    for (int mb = 0; mb < 2; mb++) {
      #pragma unroll
      for (int r = 0; r < 16; r++) {
        const int row = b0 + mb * 32 + (r & 3) + 8 * (r >> 2) + 4 * half;
        atomicAdd(&dst[(size_t)row * OUT_F + colb], acc[mb * 2][r]);
        atomicAdd(&dst[(size_t)row * OUT_F + colb + 32], acc[mb * 2 + 1][r]);
      }
    }
  } else {
    float* pd = dst + (size_t)kidx * ((size_t)4096 * OUT_F);
    #pragma unroll
    for (int mb = 0; mb < 2; mb++) {
      #pragma unroll
      for (int r = 0; r < 16; r++) {
        const int row = b0 + mb * 32 + (r & 3) + 8 * (r >> 2) + 4 * half;
        pd[(size_t)row * OUT_F + colb] = acc[mb * 2][r];
        pd[(size_t)row * OUT_F + colb + 32] = acc[mb * 2 + 1][r];
      }
    }
  }
}

// ---- split-K reduce: out = sum of 8 partial tiles ----
__global__ void kan_reduce(const float* __restrict__ part, float* __restrict__ out) {
  const size_t j = ((size_t)blockIdx.x * 256 + threadIdx.x) * 4;
  float4 a = *(const float4*)(part + j);
  #pragma unroll
  for (int s = 1; s < 8; s++) {
    float4 b = *(const float4*)(part + (size_t)s * 1048576 + j);
    a.x += b.x; a.y += b.y; a.z += b.z; a.w += b.w;
  }
  *(float4*)(out + j) = a;
}

// ---- naive fallback (only if d_ws is too small): correct, slow ----
__global__ void kan_naive(const float* __restrict__ x, const float* __restrict__ bw,
                          const float* __restrict__ sw, const float* __restrict__ sca,
                          float* __restrict__ out) {
  const int o = threadIdx.x;
  const int b = blockIdx.x;
  float accb = 0.0f, accs = 0.0f, scl = 0.0f;
  for (int i = 0; i < IN_F; i++) {
    const float xraw = x[(size_t)b * IN_F + i];
    accb += xraw * bw[(size_t)i * OUT_F + o];
    scl += fmaxf(sca[(size_t)i * OUT_F + o], 1e-7f);
    const float xc = fminf(fmaxf(xraw, -1.0f), 1.0f);
    const float xs = (xc + 1.0f) * (63.0f / (2.0f + 1e-7f));
    const float tl = xs - fminf(floorf(xs), 61.0f);
    const int kc = (int)(tl * 65.0f + 0.5f);
    const int k0 = max(0, min(kc - 8, 50));
    float e[16]; float s = 0.0f;
    #pragma unroll
    for (int j = 0; j < 16; j++) {
      float d = tl - (float)(k0 + j) * (1.0f / 65.0f);
      e[j] = __expf(-2178.0f * d * d);
      s += e[j];
    }
    const float r = __fdividef(1.0f, s + 1e-7f);
    const float* wrow = sw + ((size_t)i * OUT_F + o) * NB + k0;
    float dot = 0.0f;
    #pragma unroll
    for (int j = 0; j < 16; j++) dot += e[j] * wrow[j];
    accs += dot * r;
  }
  out[(size_t)b * OUT_F + o] = accb + accs * (scl * (1.0f / 256.0f));
}

extern "C" void kernel_launch(void* const* d_in, const int* in_sizes, int n_in,
                              void* d_out, int out_size, void* d_ws, size_t ws_size,
                              hipStream_t stream) {
  const float* x   = (const float*)d_in[0];
  const float* bw  = (const float*)d_in[1];
  const float* sw  = (const float*)d_in[2];
  const float* sca = (const float*)d_in[3];
  float* out = (float*)d_out;

  const size_t WP2_BYTES  = (size_t)IN_F * OUT_F * KP * 2;          // 10485760
  const size_t WP_OFF     = 8192;                                   // after wsp[8][256]
  const size_t PART_OFF   = WP_OFF + WP2_BYTES;                     // 10493952
  const size_t PART_BYTES = (size_t)KSPLIT * 4096 * OUT_F * 4;      // 33554432

  if (ws_size >= PART_OFF + PART_BYTES) {
    float* wsp = (float*)d_ws;
    unsigned short* wp2 = (unsigned short*)((char*)d_ws + WP_OFF);
    float* part = (float*)((char*)d_ws + PART_OFF);
    kan_scale8<<<8, 256, 0, stream>>>(sca, wsp);
    kan_pack<<<256, 256, 0, stream>>>(sw, bw, wsp, wp2);
    kan_main<<<GRID_MAIN, NTHREADS, 0, stream>>>(x, wp2, part, 0);
    kan_reduce<<<1024, 256, 0, stream>>>(part, out);
  } else if (ws_size >= PART_OFF) {
    float* wsp = (float*)d_ws;
    unsigned short* wp2 = (unsigned short*)((char*)d_ws + WP_OFF);
    (void)hipMemsetAsync(d_out, 0, (size_t)out_size * sizeof(float), stream);
    kan_scale8<<<8, 256, 0, stream>>>(sca, wsp);
    kan_pack<<<256, 256, 0, stream>>>(sw, bw, wsp, wp2);
    kan_main<<<GRID_MAIN, NTHREADS, 0, stream>>>(x, wp2, out, 1);
  } else {
    kan_naive<<<4096, 256, 0, stream>>>(x, bw, sw, sca, out);
  }
}